// Round 11
// baseline (907.988 us; speedup 1.0000x reference)
//
#include <hip/hip_runtime.h>

typedef _Float16 h16;
typedef __attribute__((ext_vector_type(8))) _Float16 h16x8;
typedef __attribute__((ext_vector_type(4))) float f32x4;
typedef unsigned int u32;

#define BARRIER() __builtin_amdgcn_s_barrier()
#define SCHEDB()  __builtin_amdgcn_sched_barrier(0)
#define VMCNT_(n) asm volatile("s_waitcnt vmcnt(" #n ")" ::: "memory")
#define VMCNT(n)  VMCNT_(n)

// ---------------- Kernel 1: A fp32 -> fp16 ----------------
__global__ __launch_bounds__(256) void cvtA_kernel(const float* __restrict__ A,
                                                   h16* __restrict__ Ah, int total8) {
  int stride = gridDim.x * blockDim.x;
  for (int i = blockIdx.x * blockDim.x + threadIdx.x; i < total8; i += stride) {
    const f32x4* p = (const f32x4*)(A + (size_t)i * 8);
    f32x4 v0 = p[0], v1 = p[1];
    h16x8 o;
    o[0] = (h16)v0[0]; o[1] = (h16)v0[1]; o[2] = (h16)v0[2]; o[3] = (h16)v0[3];
    o[4] = (h16)v1[0]; o[5] = (h16)v1[1]; o[6] = (h16)v1[2]; o[7] = (h16)v1[3];
    *(h16x8*)(Ah + (size_t)i * 8) = o;
  }
}

// ---------------- Kernel 2: dequant 2:4 int4 -> Wt [N][K] fp16 ----------------
__global__ __launch_bounds__(256) void dequant_kernel(const int* __restrict__ Bq,
    const int* __restrict__ meta, const float* __restrict__ s,
    h16* __restrict__ Wt, int K, int N, int chunksPerGroup) {
  int n = blockIdx.x * 256 + threadIdx.x;
  int chunk = blockIdx.y;
  u32 w0 = (u32)Bq[(size_t)(chunk * 2) * N + n];
  u32 w1 = (u32)Bq[(size_t)(chunk * 2 + 1) * N + n];
  float sc = s[(size_t)(chunk / chunksPerGroup) * N + n];
  h16 out[32];
#pragma unroll
  for (int gi = 0; gi < 8; ++gi) {
    int g = chunk * 8 + gi;
    int mm = meta[(size_t)g * N + n];
    u32 w = (gi < 4) ? w0 : w1;
    int j0 = (2 * gi) & 7;
    float d0 = (float)((int)((w >> (4 * j0)) & 0xFu) - 8) * sc;
    float d1 = (float)((int)((w >> (4 * j0 + 4)) & 0xFu) - 8) * sc;
    u32 enc = (0xED9C84u >> (4 * mm)) & 0xFu;
    int p0 = (int)(enc & 3u), p1 = (int)(enc >> 2);
#pragma unroll
    for (int p = 0; p < 4; ++p) {
      float v = (p == p0) ? d0 : ((p == p1) ? d1 : 0.0f);
      out[gi * 4 + p] = (h16)v;
    }
  }
  h16* dst = Wt + (size_t)n * K + chunk * 32;
  *(h16x8*)(dst + 0)  = *(h16x8*)(out + 0);
  *(h16x8*)(dst + 8)  = *(h16x8*)(out + 8);
  *(h16x8*)(dst + 16) = *(h16x8*)(out + 16);
  *(h16x8*)(dst + 24) = *(h16x8*)(out + 24);
}

// ---------------- Kernel 3 helpers ----------------
__device__ __forceinline__ void rd4(h16x8 (&d)[4][2], const h16* base, int row,
                                    int s0, int s1) {
#pragma unroll
  for (int m = 0; m < 4; ++m) {
    d[m][0] = *(const h16x8*)(base + row + m * 1024 + s0);
    d[m][1] = *(const h16x8*)(base + row + m * 1024 + s1);
  }
}
__device__ __forceinline__ void rd2(h16x8 (&d)[2][2], const h16* base, int row,
                                    int s0, int s1) {
#pragma unroll
  for (int n = 0; n < 2; ++n) {
    d[n][0] = *(const h16x8*)(base + row + n * 1024 + s0);
    d[n][1] = *(const h16x8*)(base + row + n * 1024 + s1);
  }
}
__device__ __forceinline__ void mmaQ(f32x4 (&acc)[8][4], int mo, int no,
                                     const h16x8 (&a)[4][2], const h16x8 (&b)[2][2]) {
#pragma unroll
  for (int m = 0; m < 4; ++m)
#pragma unroll
    for (int n = 0; n < 2; ++n) {
      acc[mo + m][no + n] = __builtin_amdgcn_mfma_f32_16x16x32_f16(a[m][0], b[n][0], acc[mo + m][no + n], 0, 0, 0);
      acc[mo + m][no + n] = __builtin_amdgcn_mfma_f32_16x16x32_f16(a[m][1], b[n][1], acc[mo + m][no + n], 0, 0, 0);
    }
}

// ---------------- Kernel 3: GEMM, 8-phase + register prefetch ----------------
// 256x256 tile, K-tiles of 64, 512 threads (8 waves 2Mx4N), per-wave 128x64.
// LDS: A[2buf][2half][128][64] + B same = 128 KiB -> 1 block/CU (LDS-bound),
// so VGPR budget is 256/wave: full cross-phase register prefetch affordable.
// Every MFMA burst consumes regs read in the PREVIOUS phase (>=2 barriers +
// one MFMA burst of latency cover); every phase reads for the NEXT quadrant:
//   P1: rd Bh1(T)->bf1   ; stage A(T+1,h1) ; MFMA Q00(aH0, bf0)
//   P2: rd Ah1(T)->aH1   ; stage A(T+2,h0) ; MFMA Q01(aH0, bf1)
//   P3: rd Ah0(T+1)->aH0 ; stage B(T+2,h0) ; MFMA Q11(aH1, bf1)
//   P4: rd Bh0(T+1)->spr ; stage B(T+2,h1) ; MFMA Q10(aH1, bf0)
// B sets rotate bX/bZ by tile parity (bf0/spare), bY = bf1 every tile.
// vmcnt(8) at EVERY phase end retires exactly the half-tile the next phase
// reads (ledger: entering tile T outstanding = {A(T,h1),A(T+1,h0),B(T+1,h0),
// B(T+1,h1)} = 8 loads; each phase issues 2, waits 8 -> retires the oldest).
// Tail NT-2: 8,6,4,2 ; NT-1: 0,-,-,- (stages stop -> counts tighten).
__global__ __launch_bounds__(512, 2) void gemm_kernel(const h16* __restrict__ A,
    const h16* __restrict__ Wt, const float* __restrict__ bias,
    float* __restrict__ C, int M, int N, int K) {
  __shared__ alignas(16) h16 As[2 * 2 * 8192];
  __shared__ alignas(16) h16 Bs[2 * 2 * 8192];

  const int nTilesN = N >> 8;
  const int nwg = gridDim.x;
  int bid = blockIdx.x;
  int wg = (bid & 7) * (nwg >> 3) + (bid >> 3);   // XCD swizzle (nwg%8==0)
  int tm = wg / nTilesN, tn = wg - tm * nTilesN;

  const int tid = threadIdx.x;
  const int lane = tid & 63, w = tid >> 6;
  const int wr = w >> 2, wc = w & 3;

  // ---- staging addressing (pre-swizzled global source, linear LDS dest) ----
  const int i0 = tid >> 3;                         // row within 64-row chunk
  const int sigma = (tid & 7) ^ ((tid >> 3) & 7);  // source 16B-slot
  const h16* gA_t = A + ((size_t)(tm * 256) + i0) * K + sigma * 8;
  const int rB0 = ((i0 >> 5) << 6) + (i0 & 31);    // B stripe-compact row
  const h16* gB_t = Wt + ((size_t)(tn * 256) + rB0) * K + sigma * 8;
  const int tid8 = tid * 8;
  const size_t rowK128 = (size_t)128 * K;

#define GLOAD(SRC, DST) __builtin_amdgcn_global_load_lds(                      \
    (const __attribute__((address_space(1))) void*)(SRC),                      \
    (__attribute__((address_space(3))) void*)(DST), 16, 0, 0)

#define STAGE_A(T_, mh_) do {                                                  \
    const h16* s_ = gA_t + (size_t)((mh_) * 64) * K + (T_) * 64;               \
    h16* d_ = As + ((((T_) & 1) * 2 + (mh_)) * 8192) + tid8;                   \
    GLOAD(s_, d_); GLOAD(s_ + rowK128, d_ + 4096); } while (0)

#define STAGE_B(T_, nh_) do {                                                  \
    const h16* s_ = gB_t + (size_t)((nh_) * 32) * K + (T_) * 64;               \
    h16* d_ = Bs + ((((T_) & 1) * 2 + (nh_)) * 8192) + tid8;                   \
    GLOAD(s_, d_); GLOAD(s_ + rowK128, d_ + 4096); } while (0)

  // ---- fragment read offsets (h16 units), swizzled slot = (ks*4+l16)^l7 ----
  const int ln15 = lane & 15, l16 = lane >> 4, l7 = lane & 7;
  const int aRow = (wr * 64 + ln15) * 64;
  const int bRow = (wc * 32 + ln15) * 64;
  const int sl0 = ((0 + l16) ^ l7) * 8;
  const int sl1 = ((4 + l16) ^ l7) * 8;

  f32x4 acc[8][4] = {};
  h16x8 aH0[4][2], aH1[4][2], bX[2][2], bY[2][2], bZ[2][2];
  const int NT = K >> 6;          // even, >= 4

  // prologue: stage t0 + t1(Ah0,Bh0,Bh1); pre-read aH0<-Ah0(0), bX<-Bh0(0).
  STAGE_A(0, 0); STAGE_B(0, 0); STAGE_B(0, 1); STAGE_A(0, 1);
  STAGE_A(1, 0); STAGE_B(1, 0); STAGE_B(1, 1);
  VMCNT(10); SCHEDB(); BARRIER();
  rd4(aH0, As, aRow, sl0, sl1);          // Ah0(0), buf0
  rd2(bX, Bs, bRow, sl0, sl1);           // Bh0(0), buf0
  SCHEDB(); VMCNT(8); SCHEDB(); BARRIER();

  // TILE: A1c/A0n/B1c/B0n = LDS bases for Ah1(T), Ah0(T+1), Bh1(T), Bh0(T+1).
#define TILE(T_, A1c, A0n, B1c, B0n, BF0, BSP, G1_, G2_, VM1, VM2, VM3, VM4) do { \
    /* P1 */                                                                   \
    rd2(bY, B1c, bRow, sl0, sl1);                                              \
    if (G1_) STAGE_A((T_) + 1, 1);                                             \
    SCHEDB(); BARRIER();                                                       \
    __builtin_amdgcn_s_setprio(1); mmaQ(acc, 0, 0, aH0, BF0);                  \
    __builtin_amdgcn_s_setprio(0); VM1; SCHEDB(); BARRIER();                   \
    /* P2 */                                                                   \
    rd4(aH1, A1c, aRow, sl0, sl1);                                             \
    if (G2_) STAGE_A((T_) + 2, 0);                                             \
    SCHEDB(); BARRIER();                                                       \
    __builtin_amdgcn_s_setprio(1); mmaQ(acc, 0, 2, aH0, bY);                   \
    __builtin_amdgcn_s_setprio(0); VM2; SCHEDB(); BARRIER();                   \
    /* P3 */                                                                   \
    if (G1_) rd4(aH0, A0n, aRow, sl0, sl1);                                    \
    if (G2_) STAGE_B((T_) + 2, 0);                                             \
    SCHEDB(); BARRIER();                                                       \
    __builtin_amdgcn_s_setprio(1); mmaQ(acc, 4, 2, aH1, bY);                   \
    __builtin_amdgcn_s_setprio(0); VM3; SCHEDB(); BARRIER();                   \
    /* P4 */                                                                   \
    if (G1_) rd2(BSP, B0n, bRow, sl0, sl1);                                    \
    if (G2_) STAGE_B((T_) + 2, 1);                                             \
    SCHEDB(); BARRIER();                                                       \
    __builtin_amdgcn_s_setprio(1); mmaQ(acc, 4, 0, aH1, BF0);                  \
    __builtin_amdgcn_s_setprio(0); VM4; SCHEDB(); BARRIER();                   \
  } while (0)

  for (int it = 0; it < (NT - 2) / 2; ++it) {
    const int T = it * 2;
    // even tile (buf0): bf0=bX, spare=bZ
    TILE(T,     As + 8192,  As + 16384, Bs + 8192,  Bs + 16384, bX, bZ,
         true, true, VMCNT(8), VMCNT(8), VMCNT(8), VMCNT(8));
    // odd tile (buf1): bf0=bZ, spare=bX
    TILE(T + 1, As + 24576, As,         Bs + 24576, Bs,         bZ, bX,
         true, true, VMCNT(8), VMCNT(8), VMCNT(8), VMCNT(8));
  }
  // peeled tail: tiles NT-2 (even parity), NT-1 (odd parity)
  TILE(NT - 2, As + 8192,  As + 16384, Bs + 8192,  Bs + 16384, bX, bZ,
       true,  false, VMCNT(8), VMCNT(6), VMCNT(4), VMCNT(2));
  TILE(NT - 1, As + 24576, As,         Bs + 24576, Bs,         bZ, bX,
       false, false, VMCNT(0), (void)0, (void)0, (void)0);

  // ---- epilogue ----
  int colBase = tn * 256 + wc * 64 + ln15;
  int rowBase = tm * 256 + wr * 128 + l16 * 4;
#pragma unroll
  for (int n = 0; n < 4; ++n) {
    float bv = bias[colBase + n * 16];
#pragma unroll
    for (int m = 0; m < 8; ++m) {
#pragma unroll
      for (int j = 0; j < 4; ++j) {
        C[(size_t)(rowBase + m * 16 + j) * N + colBase + n * 16] = acc[m][n][j] + bv;
      }
    }
  }
#undef TILE
#undef STAGE_A
#undef STAGE_B
#undef GLOAD
}

extern "C" void kernel_launch(void* const* d_in, const int* in_sizes, int n_in,
                              void* d_out, int out_size, void* d_ws, size_t ws_size,
                              hipStream_t stream) {
  const float* A = (const float*)d_in[0];
  const int* Bq = (const int*)d_in[1];
  const int* meta = (const int*)d_in[2];
  const float* s = (const float*)d_in[3];
  const float* bias = (const float*)d_in[4];
  float* C = (float*)d_out;

  const int N = in_sizes[4];
  const int K = (int)(((long long)in_sizes[1] * 16) / N);
  const int M = (int)((long long)in_sizes[0] / K);
  const int sRows = (int)((long long)in_sizes[3] / N);       // K/GS
  const int chunksPerGroup = (K / sRows) / 32;               // GS/32

  h16* Ah = (h16*)d_ws;                       // M*K f16 = 64 MiB
  h16* Wt = Ah + (size_t)M * K;               // N*K f16 = 32 MiB (W^T, K-major)

  cvtA_kernel<<<2048, 256, 0, stream>>>(A, Ah, (M * K) / 8);

  dim3 dgrid(N / 256, K / 32);
  dequant_kernel<<<dgrid, 256, 0, stream>>>(Bq, meta, s, Wt, K, N, chunksPerGroup);

  int grid = (M / 256) * (N / 256);
  gemm_kernel<<<grid, 512, 0, stream>>>(Ah, Wt, bias, C, M, N, K);
}

// Round 12
// 291.216 us; speedup vs baseline: 3.1179x; 3.1179x over previous
//
#include <hip/hip_runtime.h>

typedef _Float16 h16;
typedef __attribute__((ext_vector_type(8))) _Float16 h16x8;
typedef __attribute__((ext_vector_type(4))) float f32x4;
typedef unsigned int u32;

#define BARRIER() __builtin_amdgcn_s_barrier()
#define SCHEDB()  __builtin_amdgcn_sched_barrier(0)

// ------------- Kernel 1: fused aux = A fp32->fp16  +  2:4 int4 dequant -------
// Blocks [0, 2048): grid-stride cvt of A (f32 -> f16, 8 elems/thread/iter).
// Blocks [2048, ...): dequant B/meta/s -> Wt [N][K] f16 (K-major W^T).
__global__ __launch_bounds__(256) void aux_kernel(const float* __restrict__ A,
    h16* __restrict__ Ah, int total8,
    const int* __restrict__ Bq, const int* __restrict__ meta,
    const float* __restrict__ s, h16* __restrict__ Wt,
    int K, int N, int chunksPerGroup, int nBlocksN) {
  const int bid = blockIdx.x;
  if (bid < 2048) {
    int stride = 2048 * 256;
    for (int i = bid * 256 + threadIdx.x; i < total8; i += stride) {
      const f32x4* p = (const f32x4*)(A + (size_t)i * 8);
      f32x4 v0 = p[0], v1 = p[1];
      h16x8 o;
      o[0] = (h16)v0[0]; o[1] = (h16)v0[1]; o[2] = (h16)v0[2]; o[3] = (h16)v0[3];
      o[4] = (h16)v1[0]; o[5] = (h16)v1[1]; o[6] = (h16)v1[2]; o[7] = (h16)v1[3];
      *(h16x8*)(Ah + (size_t)i * 8) = o;
    }
  } else {
    const int db = bid - 2048;
    const int n = (db % nBlocksN) * 256 + threadIdx.x;   // column of W
    const int chunk = db / nBlocksN;                     // 32 dense k rows
    u32 w0 = (u32)Bq[(size_t)(chunk * 2) * N + n];
    u32 w1 = (u32)Bq[(size_t)(chunk * 2 + 1) * N + n];
    float sc = s[(size_t)(chunk / chunksPerGroup) * N + n];
    h16 out[32];
#pragma unroll
    for (int gi = 0; gi < 8; ++gi) {
      int g = chunk * 8 + gi;
      int mm = meta[(size_t)g * N + n];
      u32 w = (gi < 4) ? w0 : w1;
      int j0 = (2 * gi) & 7;
      float d0 = (float)((int)((w >> (4 * j0)) & 0xFu) - 8) * sc;
      float d1 = (float)((int)((w >> (4 * j0 + 4)) & 0xFu) - 8) * sc;
      u32 enc = (0xED9C84u >> (4 * mm)) & 0xFu;
      int p0 = (int)(enc & 3u), p1 = (int)(enc >> 2);
#pragma unroll
      for (int p = 0; p < 4; ++p) {
        float v = (p == p0) ? d0 : ((p == p1) ? d1 : 0.0f);
        out[gi * 4 + p] = (h16)v;
      }
    }
    h16* dst = Wt + (size_t)n * K + chunk * 32;
    *(h16x8*)(dst + 0)  = *(h16x8*)(out + 0);
    *(h16x8*)(dst + 8)  = *(h16x8*)(out + 8);
    *(h16x8*)(dst + 16) = *(h16x8*)(out + 16);
    *(h16x8*)(dst + 24) = *(h16x8*)(out + 24);
  }
}

// ---------------- Kernel 3: GEMM, R5-verified 8-phase schedule ----------------
// (verbatim the 267us/45.7% MfmaUtil kernel from round 5 — best measured)
// 256x256 tile, K-tiles of 64, 512 threads (8 waves 2Mx4N), per-wave 128x64.
// LDS: A[2buf][2half][128][64] + B same = 128 KiB. 4 phases per K-tile:
//   P1: read A-h0(8)+B-h0(4), stage (T+1).A-h1 ; MFMA Q(0,0)
//   P2: read B-h1(4),         stage (T+2).A-h0 ; MFMA Q(0,1)
//   P3: read A-h1(8),         stage (T+2).B-h0 ; MFMA Q(1,1)
//   P4: (no reads),           stage (T+2).B-h1 ; MFMA Q(1,0); vmcnt(6)
__global__ __launch_bounds__(512, 2) void gemm_kernel(const h16* __restrict__ A,
    const h16* __restrict__ Wt, const float* __restrict__ bias,
    float* __restrict__ C, int M, int N, int K) {
  __shared__ alignas(16) h16 As[2 * 2 * 8192];
  __shared__ alignas(16) h16 Bs[2 * 2 * 8192];

  const int nTilesN = N >> 8;
  const int nwg = gridDim.x;
  int bid = blockIdx.x;
  int wg = (bid & 7) * (nwg >> 3) + (bid >> 3);   // XCD swizzle (nwg%8==0)
  int tm = wg / nTilesN, tn = wg - tm * nTilesN;

  const int tid = threadIdx.x;
  const int lane = tid & 63, w = tid >> 6;
  const int wr = w >> 2, wc = w & 3;

  // ---- staging addressing (pre-swizzled global source, linear LDS dest) ----
  const int i0 = tid >> 3;                         // row within 64-row chunk
  const int sigma = (tid & 7) ^ ((tid >> 3) & 7);  // source 16B-slot
  const h16* gA_t = A + ((size_t)(tm * 256) + i0) * K + sigma * 8;
  const int rB0 = ((i0 >> 5) << 6) + (i0 & 31);    // B stripe-compact row
  const h16* gB_t = Wt + ((size_t)(tn * 256) + rB0) * K + sigma * 8;
  const int tid8 = tid * 8;
  const size_t rowK128 = (size_t)128 * K;

#define GLOAD(SRC, DST) __builtin_amdgcn_global_load_lds(                      \
    (const __attribute__((address_space(1))) void*)(SRC),                      \
    (__attribute__((address_space(3))) void*)(DST), 16, 0, 0)

#define STAGE_A(T_, mh_) do {                                                  \
    const h16* s_ = gA_t + (size_t)((mh_) * 64) * K + (T_) * 64;               \
    h16* d_ = As + ((((T_) & 1) * 2 + (mh_)) * 8192) + tid8;                   \
    GLOAD(s_, d_); GLOAD(s_ + rowK128, d_ + 4096); } while (0)

#define STAGE_B(T_, nh_) do {                                                  \
    const h16* s_ = gB_t + (size_t)((nh_) * 32) * K + (T_) * 64;               \
    h16* d_ = Bs + ((((T_) & 1) * 2 + (nh_)) * 8192) + tid8;                   \
    GLOAD(s_, d_); GLOAD(s_ + rowK128, d_ + 4096); } while (0)

  // ---- fragment read offsets (h16 units), swizzled slot = (ks*4+l16)^l7 ----
  const int ln15 = lane & 15, l16 = lane >> 4, l7 = lane & 7;
  const int aRow = (wr * 64 + ln15) * 64;
  const int bRow = (wc * 32 + ln15) * 64;
  const int sl0 = ((0 + l16) ^ l7) * 8;
  const int sl1 = ((4 + l16) ^ l7) * 8;

  f32x4 acc[8][4] = {};
  const int NT = K >> 6;

  // prologue: 7 half-tiles (t0 complete + t1.Ah0/Bh0/Bh1); retire t0.
  STAGE_A(0, 0); STAGE_B(0, 0); STAGE_B(0, 1); STAGE_A(0, 1);
  STAGE_A(1, 0); STAGE_B(1, 0); STAGE_B(1, 1);
  asm volatile("s_waitcnt vmcnt(6)" ::: "memory");
  SCHEDB();
  BARRIER();
  SCHEDB();

  for (int T = 0; T < NT; ++T) {
    const int buf = T & 1;
    const h16* a0 = As + (buf * 2 + 0) * 8192;
    const h16* a1 = As + (buf * 2 + 1) * 8192;
    const h16* b0 = Bs + (buf * 2 + 0) * 8192;
    const h16* b1 = Bs + (buf * 2 + 1) * 8192;
    h16x8 af[4][2], bf0[2][2], bf1[2][2];

    // ================= P1: Q(0,0) =================
#pragma unroll
    for (int m = 0; m < 4; ++m) {
      af[m][0] = *(const h16x8*)(a0 + aRow + m * 1024 + sl0);
      af[m][1] = *(const h16x8*)(a0 + aRow + m * 1024 + sl1);
    }
#pragma unroll
    for (int n = 0; n < 2; ++n) {
      bf0[n][0] = *(const h16x8*)(b0 + bRow + n * 1024 + sl0);
      bf0[n][1] = *(const h16x8*)(b0 + bRow + n * 1024 + sl1);
    }
    if (T + 1 < NT) STAGE_A(T + 1, 1);
    asm volatile("s_waitcnt lgkmcnt(8)" ::: "memory");
    SCHEDB();
    BARRIER();
    asm volatile("s_waitcnt lgkmcnt(0)" ::: "memory");
    SCHEDB();
    __builtin_amdgcn_s_setprio(1);
#pragma unroll
    for (int m = 0; m < 4; ++m)
#pragma unroll
      for (int n = 0; n < 2; ++n) {
        acc[m][n] = __builtin_amdgcn_mfma_f32_16x16x32_f16(af[m][0], bf0[n][0], acc[m][n], 0, 0, 0);
        acc[m][n] = __builtin_amdgcn_mfma_f32_16x16x32_f16(af[m][1], bf0[n][1], acc[m][n], 0, 0, 0);
      }
    __builtin_amdgcn_s_setprio(0);
    SCHEDB();
    BARRIER();

    // ================= P2: Q(0,1) =================
#pragma unroll
    for (int n = 0; n < 2; ++n) {
      bf1[n][0] = *(const h16x8*)(b1 + bRow + n * 1024 + sl0);
      bf1[n][1] = *(const h16x8*)(b1 + bRow + n * 1024 + sl1);
    }
    if (T + 2 < NT) STAGE_A(T + 2, 0);
    SCHEDB();
    BARRIER();
    asm volatile("s_waitcnt lgkmcnt(0)" ::: "memory");
    SCHEDB();
    __builtin_amdgcn_s_setprio(1);
#pragma unroll
    for (int m = 0; m < 4; ++m)
#pragma unroll
      for (int n = 0; n < 2; ++n) {
        acc[m][2 + n] = __builtin_amdgcn_mfma_f32_16x16x32_f16(af[m][0], bf1[n][0], acc[m][2 + n], 0, 0, 0);
        acc[m][2 + n] = __builtin_amdgcn_mfma_f32_16x16x32_f16(af[m][1], bf1[n][1], acc[m][2 + n], 0, 0, 0);
      }
    __builtin_amdgcn_s_setprio(0);
    SCHEDB();
    BARRIER();

    // ================= P3: Q(1,1) =================
#pragma unroll
    for (int m = 0; m < 4; ++m) {
      af[m][0] = *(const h16x8*)(a1 + aRow + m * 1024 + sl0);
      af[m][1] = *(const h16x8*)(a1 + aRow + m * 1024 + sl1);
    }
    if (T + 2 < NT) STAGE_B(T + 2, 0);
    SCHEDB();
    BARRIER();
    asm volatile("s_waitcnt lgkmcnt(0)" ::: "memory");
    SCHEDB();
    __builtin_amdgcn_s_setprio(1);
#pragma unroll
    for (int m = 0; m < 4; ++m)
#pragma unroll
      for (int n = 0; n < 2; ++n) {
        acc[4 + m][2 + n] = __builtin_amdgcn_mfma_f32_16x16x32_f16(af[m][0], bf1[n][0], acc[4 + m][2 + n], 0, 0, 0);
        acc[4 + m][2 + n] = __builtin_amdgcn_mfma_f32_16x16x32_f16(af[m][1], bf1[n][1], acc[4 + m][2 + n], 0, 0, 0);
      }
    __builtin_amdgcn_s_setprio(0);
    SCHEDB();
    BARRIER();

    // ================= P4: Q(1,0) =================
    if (T + 2 < NT) STAGE_B(T + 2, 1);
    SCHEDB();
    BARRIER();
    SCHEDB();
    __builtin_amdgcn_s_setprio(1);
#pragma unroll
    for (int m = 0; m < 4; ++m)
#pragma unroll
      for (int n = 0; n < 2; ++n) {
        acc[4 + m][n] = __builtin_amdgcn_mfma_f32_16x16x32_f16(af[m][0], bf0[n][0], acc[4 + m][n], 0, 0, 0);
        acc[4 + m][n] = __builtin_amdgcn_mfma_f32_16x16x32_f16(af[m][1], bf0[n][1], acc[4 + m][n], 0, 0, 0);
      }
    __builtin_amdgcn_s_setprio(0);
    SCHEDB();
    if (T < NT - 2) {
      asm volatile("s_waitcnt vmcnt(6)" ::: "memory");
    } else if (T == NT - 2) {
      asm volatile("s_waitcnt vmcnt(0)" ::: "memory");
    }
    SCHEDB();
    BARRIER();
    SCHEDB();
  }

  // ---- epilogue ----
  int colBase = tn * 256 + wc * 64 + ln15;
  int rowBase = tm * 256 + wr * 128 + l16 * 4;
#pragma unroll
  for (int n = 0; n < 4; ++n) {
    float bv = bias[colBase + n * 16];
#pragma unroll
    for (int m = 0; m < 8; ++m) {
#pragma unroll
      for (int j = 0; j < 4; ++j) {
        C[(size_t)(rowBase + m * 16 + j) * N + colBase + n * 16] = acc[m][n][j] + bv;
      }
    }
  }
#undef STAGE_A
#undef STAGE_B
#undef GLOAD
}

extern "C" void kernel_launch(void* const* d_in, const int* in_sizes, int n_in,
                              void* d_out, int out_size, void* d_ws, size_t ws_size,
                              hipStream_t stream) {
  const float* A = (const float*)d_in[0];
  const int* Bq = (const int*)d_in[1];
  const int* meta = (const int*)d_in[2];
  const float* s = (const float*)d_in[3];
  const float* bias = (const float*)d_in[4];
  float* C = (float*)d_out;

  const int N = in_sizes[4];
  const int K = (int)(((long long)in_sizes[1] * 16) / N);
  const int M = (int)((long long)in_sizes[0] / K);
  const int sRows = (int)((long long)in_sizes[3] / N);       // K/GS
  const int chunksPerGroup = (K / sRows) / 32;               // GS/32
  const int nBlocksN = N / 256;

  h16* Ah = (h16*)d_ws;                       // M*K f16 = 64 MiB
  h16* Wt = Ah + (size_t)M * K;               // N*K f16 = 32 MiB (W^T, K-major)

  int auxGrid = 2048 + nBlocksN * (K / 32);
  aux_kernel<<<auxGrid, 256, 0, stream>>>(A, Ah, (M * K) / 8, Bq, meta, s, Wt,
                                          K, N, chunksPerGroup, nBlocksN);

  int grid = (M / 256) * (N / 256);
  gemm_kernel<<<grid, 512, 0, stream>>>(Ah, Wt, bias, C, M, N, K);
}